// Round 13
// baseline (207.955 us; speedup 1.0000x reference)
//
#include <hip/hip_runtime.h>
#include <cstdint>

#define IW 1536
#define IH 1536
#define TOPK 100
#define CAPB 128       // above-threshold keys (provably <=99 real entries)
#define CAPT 8192      // tie-class cap per channel (expected ~4.6k)
#define BF_INF16 0x7F7Fu  // bf16 max-finite stand-in for +inf (inf-inf=NaN in comparator)

#define NBLK 192       // proven co-resident; 576/192 = 3 tiles/blk
#define VBTOT 576      // virtual scan tiles (4096 px each), static partition
#define LTCAP 1024     // per-block LDS tie buffer (expected ~70/block)

#define CREPS 3        // MEASUREMENT ROUND: phase C runs 3x (idempotent); tC=(dur-57.4)/2

typedef unsigned u32; typedef unsigned long long u64; typedef unsigned short u16;

// ---- workspace layout (u32 offsets) ----
#define OH1   0                   // 2*2048: level-1 hist (bins of enc>>5), peaks only
#define OCNT  4096                // [0,1] unused, [2,3] cntB, [4,5] cntT
#define OSEL  4102                // D0,D1,above0,above1
#define OLSD  4106                // (retired — kept for layout stability)
#define OBAR  4170                // 2 grid-barrier counters (zeroed)
#define OZEND 4176                // end of zeroed region
#define OSCR  4176                // scratch: phase-C tie-index lists (2*CAPT u32)
#define OLB   (OSCR + 2*CAPT + 2) // 2*CAPB u64 keys (8-aligned: even u32 offset)
#define OLT   (OLB + 4*CAPB)      // 2*CAPT u64 tie lists
#define OLSDV (OLT + 4*CAPT)      // NBLK*64 u32 per-block lsd vectors (non-atomic; all 64 written)

__device__ __forceinline__ u32 enc16(u32 b){ b &= 0xFFFFu; return (b & 0x8000u) ? ((~b)&0xFFFFu) : (b|0x8000u); }
__device__ __forceinline__ u32 dec16(u32 e){ return (e & 0x8000u) ? (e^0x8000u) : ((~e)&0xFFFFu); }
__device__ __forceinline__ float up16(u32 b){ return __uint_as_float((b&0xFFFFu)<<16); }
__device__ __forceinline__ u16 f2bf(float f){ u32 u=__float_as_uint(f); return (u16)((u + 0x7FFFu + ((u>>16)&1u))>>16); }

// packed u16 max (both channels at once); heat is positive bf16 so raw-u16 order == float order
__device__ __forceinline__ u32 pkmaxu16(u32 a, u32 b){
  u32 d; asm("v_pk_max_u16 %0, %1, %2" : "=v"(d) : "v"(a), "v"(b)); return d;
}

// one wave: largest bin D in bins[0..2047] with suffix-count >= need;
// Aout = count strictly above D.
__device__ __forceinline__ void wave_sel2048(const u32* bins, u32 need, int* Dout, u32* Aout){
  int lane = threadIdx.x & 63;
  u32 s = 0;
  #pragma unroll
  for(int k=0;k<32;++k) s += bins[lane*32+k];
  u32 c = s;
  #pragma unroll
  for(int off=1;off<64;off<<=1){
    u32 v = __shfl_down(c, off, 64);
    if(lane + off < 64) c += v;
  }
  u32 cnext = __shfl_down(c, 1, 64); if(lane==63) cnext = 0u;
  u64 m = __ballot(c >= need);
  if(m == 0ull){ if(lane==0){ *Dout = 0; *Aout = 0u; } return; }
  int L = 63 - __builtin_clzll((unsigned long long)m);
  if(lane == L){
    u32 above = cnext; int D = 32*L;
    for(int b=32*L+31; b>=32*L; --b){
      u32 h = bins[b];
      if(above + h >= need){ D = b; break; }
      above += h;
    }
    *Dout = D; *Aout = above;
  }
}

// LDS overlay: phases A/B (hist + lsd + emit buffers) vs phase C are time-disjoint
union SMem {
  struct {                       // phases A1/B'/A2: ~34.3 KB
    u32 lh[4096];
    u32 lsdl[64];
    u64 bbuf[2][CAPB];           // per-block B-class buffer (<=99 total grid-wide)
    u64 tbuf[2][LTCAP];          // per-block tie buffer (expected ~70/block)
  } ab;
  struct {                       // phase C: ~15.7 KB (single channel per block)
    u32 h2s[2048];
    u64 keysS[CAPB];
    u32 selS[CAPB];
    u32 wbitsS[64];
    u32 lsdS[32];
    u32 hdr[10];
    float val[TOPK]; int vidx[TOPK];
    float cbox[TOPK][4]; float cscore[TOPK]; float area[TOPK];
    int sup[TOPK]; int slotv[TOPK];
    u64 nbits[2*TOPK];
  } c;
};

__device__ __forceinline__ void grid_arrive(u32* ctr){
  __hip_atomic_fetch_add(ctr, 1u, __ATOMIC_RELEASE, __HIP_MEMORY_SCOPE_AGENT);
}
// relaxed poll + single acquire fence (r12; neutral but clean)
__device__ __forceinline__ void grid_wait(u32* ctr, u32 target){
  while(__hip_atomic_load(ctr, __ATOMIC_RELAXED, __HIP_MEMORY_SCOPE_AGENT) < target)
    __builtin_amdgcn_s_sleep(2);
  __builtin_amdgcn_fence(__ATOMIC_ACQUIRE, "agent");
}

__global__ __launch_bounds__(1024, 4) void fused_kernel(
    const u32* __restrict__ hm, u32* __restrict__ ws,
    const u32* __restrict__ szm, const u16* __restrict__ offm,
    const u16* __restrict__ orig, u16* __restrict__ out){
  __shared__ SMem S;
  __shared__ int Dsh[2]; __shared__ u32 Ash[2];
  __shared__ u32 bcntS[2], tcntS[2], bbaseS[2], tbaseS[2];
  __shared__ int selcS, selc2S, BvS, LshS, tcS;
  __shared__ u64 suppS[2];
  __shared__ int cS, srS, scS;

  int tid = threadIdx.x, lane = tid & 63;

  // ================= phase A1: peak histogram only (packed separable max) ======
  for(int i=tid;i<4096;i+=1024) S.ab.lh[i]=0u;
  __syncthreads();
  for(int vb = blockIdx.x; vb < VBTOT; vb += NBLK){
    int p = (vb*1024 + tid)*4;
    int y = p / IW, x = p - y*IW;
    const u32* R1 = hm + y*IW;
    const u32* R0 = y ? R1 - IW : R1;
    const u32* R2 = (y < IH-1) ? R1 + IW : R1;
    uint4 c0 = *(const uint4*)(R0+x), c1 = *(const uint4*)(R1+x), c2 = *(const uint4*)(R2+x);
    int xl = x ? x-1 : 0, xr = (x+4 < IW) ? x+4 : IW-1;
    u32 a0[6] = {R0[xl], c0.x, c0.y, c0.z, c0.w, R0[xr]};
    u32 a1[6] = {R1[xl], c1.x, c1.y, c1.z, c1.w, R1[xr]};
    u32 a2[6] = {R2[xl], c2.x, c2.y, c2.z, c2.w, R2[xr]};
    u32 v[6], w[6];
    #pragma unroll
    for(int k=0;k<6;++k){ w[k] = pkmaxu16(a0[k], a2[k]); v[k] = pkmaxu16(w[k], a1[k]); }
    #pragma unroll
    for(int j=0;j<4;++j){
      u32 m = pkmaxu16(pkmaxu16(v[j], w[j+1]), v[j+2]);   // 8 neighbors, center excluded
      u32 cc = a1[j+1];
      u32 cl = cc & 0xFFFFu, chv = cc >> 16;
      if(cl  >= (m & 0xFFFFu)) atomicAdd(&S.ab.lh[enc16(cl)>>5], 1u);
      if(chv >= (m >> 16))     atomicAdd(&S.ab.lh[2048 + (enc16(chv)>>5)], 1u);
    }
  }
  __syncthreads();
  for(int i=tid;i<4096;i+=1024) if(S.ab.lh[i]) atomicAdd(&ws[OH1+i], S.ab.lh[i]);

  // ---- grid barrier 1 ----
  __syncthreads();
  if(tid==0){ grid_arrive(&ws[OBAR]); grid_wait(&ws[OBAR], (u32)NBLK); }
  __syncthreads();

  // ================= phase B': every block computes D/above from global hist ====
  for(int i=tid;i<4096;i+=1024) S.ab.lh[i] = ws[OH1+i];
  if(tid < 64) S.ab.lsdl[tid] = 0u;
  if(tid < 2){ bcntS[tid] = 0u; tcntS[tid] = 0u; }
  __syncthreads();
  if(tid < 64)       wave_sel2048(S.ab.lh,        (u32)TOPK, &Dsh[0], &Ash[0]);
  else if(tid < 128) wave_sel2048(S.ab.lh + 2048, (u32)TOPK, &Dsh[1], &Ash[1]);
  __syncthreads();
  if(blockIdx.x == 0 && tid < 2){ ws[OSEL+tid] = (u32)Dsh[tid]; ws[OSEL+2+tid] = Ash[tid]; }

  // ============ phase A2: prefiltered re-scan, LDS-aggregated sparse emission ====
  {
    u32 thrD0 = (u32)Dsh[0] << 5, thrD1 = (u32)Dsh[1] << 5;
    u64* listBw = (u64*)(ws + OLB);
    u64* tieW   = (u64*)(ws + OLT);
    for(int vb = blockIdx.x; vb < VBTOT; vb += NBLK){
      int p = (vb*1024 + tid)*4;
      int y = p / IW, x = p - y*IW;
      const u32* R1 = hm + y*IW;
      uint4 c1v = *(const uint4*)(R1+x);
      u32 cen[4] = {c1v.x, c1v.y, c1v.z, c1v.w};
      const u32* R0 = y ? R1 - IW : R1;
      const u32* R2 = (y < IH-1) ? R1 + IW : R1;
      #pragma unroll
      for(int j=0;j<4;++j){
        u32 cc = cen[j];
        u32 cl = cc & 0xFFFFu, chv = cc >> 16;
        u32 e0 = enc16(cl), e1 = enc16(chv);
        bool cand0 = (e0 >= thrD0), cand1 = (e1 >= thrD1);
        if(!(cand0 || cand1)) continue;         // ~0.4% pass rate
        int xx = x + j;
        int xm = xx ? xx-1 : 0, xp = (xx+1 < IW) ? xx+1 : IW-1;
        u32 n0a=R0[xm], n0b=R0[xx], n0c=R0[xp];
        u32 n1a=R1[xm],             n1c=R1[xp];
        u32 n2a=R2[xm], n2b=R2[xx], n2c=R2[xp];
        u32 m0=0u, m1=0u, t;
        t=n0a&0xFFFFu; m0=t>m0?t:m0;  t=n0a>>16; m1=t>m1?t:m1;
        t=n0b&0xFFFFu; m0=t>m0?t:m0;  t=n0b>>16; m1=t>m1?t:m1;
        t=n0c&0xFFFFu; m0=t>m0?t:m0;  t=n0c>>16; m1=t>m1?t:m1;
        t=n1a&0xFFFFu; m0=t>m0?t:m0;  t=n1a>>16; m1=t>m1?t:m1;
        t=n1c&0xFFFFu; m0=t>m0?t:m0;  t=n1c>>16; m1=t>m1?t:m1;
        t=n2a&0xFFFFu; m0=t>m0?t:m0;  t=n2a>>16; m1=t>m1?t:m1;
        t=n2b&0xFFFFu; m0=t>m0?t:m0;  t=n2b>>16; m1=t>m1?t:m1;
        t=n2c&0xFFFFu; m0=t>m0?t:m0;  t=n2c>>16; m1=t>m1?t:m1;
        u32 idx = (u32)(p + j);
        u64 key0 = ((u64)e0<<32) | (u32)(~idx);
        u64 key1 = ((u64)e1<<32) | (u32)(~idx);
        if(cand0 && cl >= m0){
          if((e0>>5) > (u32)Dsh[0]){
            u32 pos = atomicAdd(&bcntS[0], 1u);       // <=99 grid-wide: always fits
            if(pos < CAPB) S.ab.bbuf[0][pos] = key0;
          } else {
            u32 pos = atomicAdd(&tcntS[0], 1u);
            if(pos < LTCAP) S.ab.tbuf[0][pos] = key0;
            else { u32 g = atomicAdd(&ws[OCNT+4], 1u); if(g < CAPT) tieW[g] = key0; }
            atomicAdd(&S.ab.lsdl[e0 & 31u], 1u);
          }
        }
        if(cand1 && chv >= m1){
          if((e1>>5) > (u32)Dsh[1]){
            u32 pos = atomicAdd(&bcntS[1], 1u);
            if(pos < CAPB) S.ab.bbuf[1][pos] = key1;
          } else {
            u32 pos = atomicAdd(&tcntS[1], 1u);
            if(pos < LTCAP) S.ab.tbuf[1][pos] = key1;
            else { u32 g = atomicAdd(&ws[OCNT+5], 1u); if(g < CAPT) tieW[CAPT + g] = key1; }
            atomicAdd(&S.ab.lsdl[32 + (e1 & 31u)], 1u);
          }
        }
      }
    }
    __syncthreads();
    // ---- block-level flush ----
    if(tid < 64) ws[OLSDV + (u32)blockIdx.x*64u + (u32)tid] = S.ab.lsdl[tid];
    if(tid >= 64 && tid < 66){
      int c2 = tid - 64;
      u32 n = bcntS[c2]; if(n > CAPB) n = CAPB;
      bcntS[c2] = n;
      bbaseS[c2] = n ? atomicAdd(&ws[OCNT+2+c2], n) : 0u;
    } else if(tid >= 66 && tid < 68){
      int ch2 = tid - 66;
      u32 n = tcntS[ch2]; if(n > LTCAP) n = LTCAP;
      tcntS[ch2] = n;
      tbaseS[ch2] = n ? atomicAdd(&ws[OCNT+4+ch2], n) : 0u;
    }
    __syncthreads();
    for(int ch2=0; ch2<2; ++ch2){
      u32 n = bcntS[ch2], base = bbaseS[ch2];
      for(u32 i=tid;i<n;i+=1024){
        u32 g = base + i;
        if(g < CAPB) listBw[ch2*CAPB + g] = S.ab.bbuf[ch2][i];
      }
      n = tcntS[ch2]; base = tbaseS[ch2];
      for(u32 i=tid;i<n;i+=1024){
        u32 g = base + i;
        if(g < CAPT) tieW[ch2*CAPT + g] = S.ab.tbuf[ch2][i];
      }
    }
  }

  // ---- grid barrier 2: blocks >=2 arrive and exit; blocks 0,1 spin ----
  __syncthreads();
  if(tid==0) grid_arrive(&ws[OBAR+1]);
  if(blockIdx.x >= 2) return;
  if(tid==0) grid_wait(&ws[OBAR+1], (u32)NBLK);
  __syncthreads();

  // ================= phase C: finalize — AMPLIFIED x CREPS (idempotent re-run) ====
  for(int rep = 0; rep < CREPS; ++rep){
    int ch = (int)blockIdx.x;

    // ---- C.1: batched control loads + zeroing (re-inits all per-rep state) ----
    if(tid < 10) S.c.hdr[tid] = ws[OCNT + tid];      // OCNT..OSEL contiguous
    if(tid < 32) S.c.lsdS[tid] = 0u;
    for(int i=tid;i<2048;i+=1024) S.c.h2s[i] = 0u;
    if(tid < 64) S.c.wbitsS[tid] = 0u;
    if(tid == 0){ selcS = 0; selc2S = 0; BvS = 0; LshS = 0; tcS = 0; }
    if(tid < TOPK){ S.c.val[tid]=0.0f; S.c.vidx[tid]=0; }
    __syncthreads();

    int nB = (int)S.c.hdr[2+ch]; if(nB > CAPB) nB = CAPB;
    int nT = (int)S.c.hdr[4+ch]; if(nT > CAPT) nT = CAPT;
    int D  = (int)S.c.hdr[6+ch];
    u32 above = S.c.hdr[8+ch];
    const u64* listB = ((const u64*)(ws + OLB)) + ch*CAPB;
    const u64* tie   = ((const u64*)(ws + OLT)) + ch*CAPT;
    u32* tidxG = ws + OSCR + ch*CAPT;                // scratch (rewritten each rep, same set)

    // ---- C.1b: reduce per-block lsd vectors ----
    if(tid < 512){
      int c2 = tid & 31, g = tid >> 5;               // 16 groups x 32 classes
      u32 s = 0;
      for(int b = g; b < NBLK; b += 16) s += ws[OLSDV + (u32)b*64u + (u32)(ch*32 + c2)];
      if(s) atomicAdd(&S.c.lsdS[c2], s);
    }
    for(int i=tid;i<nB;i+=1024) S.c.keysS[i] = listB[i];
    __syncthreads();

    // ---- C.2: wave-parallel threshold pick ----
    if(tid < 64){
      u32 h = (lane < 32) ? S.c.lsdS[lane] : 0u;
      u32 c = h;
      #pragma unroll
      for(int off=1;off<32;off<<=1){
        u32 v = __shfl_down(c, off, 64);
        if(lane + off < 32) c += v;
      }
      u32 need2 = (u32)TOPK - above;     // in [1,100]
      u64 m = __ballot(lane >= 1 && lane < 32 && c >= need2);
      if(lane == 0){
        LshS = m ? (63 - __builtin_clzll((unsigned long long)m)) : 0;
        selcS = nB;
      }
    }
    __syncthreads();
    u32 thr = ((u32)D<<5) | (u32)LshS;
    float tval = up16(dec16(thr));

    // ---- C.3: single streamed pass (ballot-aggregated tie append) ----
    for(int base2=0; base2<nT; base2+=1024){
      int i = base2 + tid;
      bool act = (i < nT);
      u64 k = 0; u32 e = 0, idx = 0;
      if(act){ k = tie[i]; e = (u32)(k>>32); idx = ~(u32)(k & 0xFFFFFFFFu); }
      if(act && e > thr){
        int pos = atomicAdd(&selcS, 1); if(pos < CAPB) S.c.keysS[pos] = k;
      }
      bool isT = act && (e == thr);
      u64 mk = __ballot(isT);
      if(mk){
        u32 cw = __popcll(mk), b;
        if(lane==0) b = (u32)atomicAdd(&tcS, (int)cw);
        b = __shfl(b, 0);
        if(isT){
          u32 pos = b + __popcll(mk & ((1ull<<lane)-1ull));
          if(pos < CAPT) tidxG[pos] = idx;
        }
      }
      if(isT) atomicAdd(&S.c.h2s[idx>>11], 1u);
    }
    __syncthreads();

    // ---- C.4: rank-sort keys; wave-parallel B-select ----
    int nA = selcS; if(nA > CAPB) nA = CAPB; if(nA > TOPK) nA = TOPK;
    int need = TOPK - nA;
    if(tid < nA){
      u64 kreg = S.c.keysS[tid];
      int r = 0;
      for(int j=0;j<nA;++j) r += (S.c.keysS[j] > kreg);
      if(r < TOPK){
        S.c.val[r] = up16(dec16((u32)(kreg>>32)));
        S.c.vidx[r] = (int)(~(u32)(kreg & 0xFFFFFFFFu));
      }
    }
    if(tid < 64){
      const u32* hh = S.c.h2s;
      int base = lane*32;
      u32 s = 0;
      #pragma unroll
      for(int k2=0;k2<32;++k2) s += hh[base+k2];
      u32 c = s;
      #pragma unroll
      for(int off=1;off<64;off<<=1){
        u32 v = __shfl_up(c, off, 64);
        if(lane >= off) c += v;
      }
      u64 m = __ballot(need > 0 && c >= (u32)need);
      int L = m ? (int)(__ffsll((unsigned long long)m) - 1) : -1;
      if(L >= 0 && lane == L){
        u32 hb[32];
        #pragma unroll
        for(int k2=0;k2<32;++k2) hb[k2] = hh[base+k2];
        u32 cum2 = c - s;
        int Bsel = base;
        #pragma unroll
        for(int k2=0;k2<32;++k2){
          if(cum2 + hb[k2] >= (u32)need){ Bsel = base+k2; break; }
          cum2 += hb[k2];
        }
        BvS = Bsel;
      }
    }
    __syncthreads();

    // ---- C.5: compact-tie pass ----
    int B = BvS;
    int tc = tcS; if(tc > CAPT) tc = CAPT;
    if(need > 0){
      for(int i=tid;i<tc;i+=1024){
        u32 idx = tidxG[i];
        int b = (int)(idx>>11);
        if(b < B){
          int pos = atomicAdd(&selc2S, 1);
          if(pos < CAPB) S.c.selS[pos] = idx;
        } else if(b == B){
          atomicOr(&S.c.wbitsS[(idx&2047)>>5], 1u<<(idx&31));
        }
      }
    }
    __syncthreads();

    // ---- C.6: order tie winners ----
    int sc = selc2S; if(sc > CAPB) sc = CAPB;
    if(need > 0 && tid < sc){
      u32 v = S.c.selS[tid];
      int r = 0;
      for(int j=0;j<sc;++j) r += (S.c.selS[j] < v);
      if(nA + r < TOPK){ S.c.val[nA+r] = tval; S.c.vidx[nA+r] = (int)v; }
    }
    if(need > 0 && tid < 64){
      u32 bits = S.c.wbitsS[tid];
      u32 cnt = __popc(bits);
      u32 incl = cnt;
      #pragma unroll
      for(int off=1;off<64;off<<=1){
        u32 v = __shfl_up(incl, off, 64);
        if(lane >= off) incl += v;
      }
      int excl = (int)(incl - cnt);
      int rem = need - sc;
      int pos = nA + sc + excl;
      int j = 0;
      while(bits){
        int l = __ffs(bits) - 1; bits &= bits - 1;
        if(excl + j < rem && pos + j < TOPK){
          S.c.val[pos+j] = tval;
          S.c.vidx[pos+j] = (int)(((u32)B<<11) | ((u32)tid<<5) | (u32)l);
        }
        ++j;
      }
    }
    __syncthreads();

    // ================= per-channel epilogues (structured; no early return) ======
    float ry = up16(orig[0]) / 1536.0f;
    float rx = up16(orig[1]) / 1536.0f;

    if(ch == 1){
      if(tid == 0){ cS = 0; srS = 0; scS = 0; }
      __syncthreads();
      if(tid < TOPK && S.c.val[tid] > 0.5f){
        atomicAdd(&cS, 1);
        atomicAdd(&srS, S.c.vidx[tid] / IW);
        atomicAdd(&scS, S.c.vidx[tid] % IW);
      }
      if(tid < TOPK) out[610 + tid] = f2bf(S.c.val[tid] > 0.5f ? S.c.val[tid] : -1.0f);
      __syncthreads();
      if(tid == 0){
        int c = cS < 1 ? 1 : cS;
        int meanr = srS / c, meanc = scS / c;
        float lfy = (float)meanr, lfx = (float)meanc;
        out[600] = f2bf(lfy * ry);
        out[601] = f2bf(lfx * rx);
        const u16* op = offm + ((size_t)meanr*IW + meanc)*8;
        for(int p=0;p<4;++p){
          out[602 + p*2 + 0] = f2bf((lfy - up16(op[p*2+0])) * ry);
          out[602 + p*2 + 1] = f2bf((lfx - up16(op[p*2+1])) * rx);
        }
      }
    } else {
      // ch == 0: boxes + NMS + out[0..599]
      if(tid < TOPK){
        int idx = S.c.vidx[tid];
        int r = idx / IW, c = idx - r*IW;
        float score = S.c.val[tid];
        u32 sz = szm[idx];
        float sy = up16(sz), sx = up16(sz>>16);
        float cy = (float)r, cx = (float)c;
        float tly = fmaxf(cy - sy*0.5f, 0.0f);
        float tlx = fmaxf(cx - sx*0.5f, 0.0f);
        float bry = fminf(cy + sy*0.5f, 1535.0f);
        float brx = fminf(cx + sx*0.5f, 1535.0f);
        bool mk = score > 0.3f;
        float b0 = mk ? tly*ry : -1.0f;
        float b1 = mk ? tlx*rx : -1.0f;
        float b2 = mk ? bry*ry : -1.0f;
        float b3 = mk ? brx*rx : -1.0f;
        S.c.cbox[tid][0]=b0; S.c.cbox[tid][1]=b1; S.c.cbox[tid][2]=b2; S.c.cbox[tid][3]=b3;
        S.c.cscore[tid] = mk ? score : -1.0f;
        S.c.area[tid] = fmaxf(b2-b0,0.0f) * fmaxf(b3-b1,0.0f);
      }
      if(tid < 2*TOPK) S.c.nbits[tid] = 0ull;
      __syncthreads();

      for(int t=tid; t<TOPK*TOPK; t+=512){
        int i = t / TOPK, j = t - i*TOPK;
        if(j > i){
          float iy1 = fmaxf(S.c.cbox[i][0], S.c.cbox[j][0]);
          float ix1 = fmaxf(S.c.cbox[i][1], S.c.cbox[j][1]);
          float iy2 = fminf(S.c.cbox[i][2], S.c.cbox[j][2]);
          float ix2 = fminf(S.c.cbox[i][3], S.c.cbox[j][3]);
          float inter = fmaxf(iy2-iy1,0.0f) * fmaxf(ix2-ix1,0.0f);
          float uni = (S.c.area[i] + S.c.area[j]) - inter;
          if(inter / fmaxf(uni, 1e-8f) > 0.5f)
            atomicOr(&S.c.nbits[i*2 + (j>>6)], 1ull << (j&63));
        }
      }
      __syncthreads();
      // serial recurrence, register-batched LDS prefetch (10 rows/batch)
      if(tid == 0){
        u64 s0 = 0ull, s1 = 0ull;
        for(int base=0;base<TOPK;base+=10){
          u64 buf[20];
          #pragma unroll
          for(int k=0;k<20;++k) buf[k] = S.c.nbits[2*base+k];
          #pragma unroll
          for(int k=0;k<10;++k){
            int i = base+k;
            bool su = (i<64) ? ((s0>>i)&1ull) : ((s1>>(i-64))&1ull);
            if(!su){ s0 |= buf[2*k]; s1 |= buf[2*k+1]; }
          }
        }
        suppS[0] = s0; suppS[1] = s1;
      }
      __syncthreads();
      if(tid < TOPK) S.c.sup[tid] = (int)((suppS[tid>>6] >> (tid&63)) & 1ull);
      __syncthreads();

      if(tid < TOPK){
        int kbefore = 0, sbefore = 0, ktot = 0;
        for(int j=0;j<TOPK;++j){
          int sj = S.c.sup[j];
          ktot += (1 - sj);
          if(j < tid){ kbefore += (1 - sj); sbefore += sj; }
        }
        int slot = S.c.sup[tid] ? (ktot + sbefore) : kbefore;
        S.c.slotv[slot] = tid;
      }
      __syncthreads();

      if(tid < TOPK){
        int s = S.c.slotv[tid];
        bool ks = !S.c.sup[s];
        u16 row[6];
        if(ks){
          for(int d=0;d<4;++d){
            float v = S.c.cbox[s][d];
            row[d] = (v == -1.0f || v == 0.0f) ? (u16)BF_INF16 : f2bf(v);
          }
          row[4] = f2bf(S.c.cscore[s]);
        } else {
          for(int d=0;d<4;++d) row[d] = (u16)BF_INF16;
          row[4] = 0;
        }
        row[5] = 0;
        for(int d=0;d<6;++d) out[tid*6 + d] = row[d];
      }
    }
    __syncthreads();   // rep boundary: all writes/readers settled before re-init
  }
}

extern "C" void kernel_launch(void* const* d_in, const int* in_sizes, int n_in,
                              void* d_out, int out_size, void* d_ws, size_t ws_size,
                              hipStream_t stream) {
  const u32* heat = (const u32*)d_in[0];   // bf16 pairs (ch1<<16|ch0) per pixel
  const u16* offm = (const u16*)d_in[1];
  const u32* szm  = (const u32*)d_in[2];
  const u16* orig = (const u16*)d_in[3];
  u16* out = (u16*)d_out;
  u32* ws = (u32*)d_ws;

  hipMemsetAsync(ws, 0, OZEND*sizeof(u32), stream);   // hist + counters + sel + barriers
  fused_kernel<<<NBLK, 1024, 0, stream>>>(heat, ws, szm, offm, orig, out);
}

// Round 14
// 168.479 us; speedup vs baseline: 1.2343x; 1.2343x over previous
//
#include <hip/hip_runtime.h>
#include <cstdint>

#define IW 1536
#define IH 1536
#define TOPK 100
#define CAPB 128       // above-threshold keys (provably <=99 real entries)
#define CAPT 8192      // tie-class cap per channel (expected ~4.6k)
#define BF_INF16 0x7F7Fu  // bf16 max-finite stand-in for +inf (inf-inf=NaN in comparator)

#define NBLK 192       // proven co-resident; 576/192 = 3 tiles/blk
#define VBTOT 576      // virtual scan tiles (4096 px each), static partition
#define LTCAP 1024     // per-block LDS tie buffer (expected ~70/block)
#define NREP 4         // A1 hist replicas (hot-bin chain 192 -> 48)

typedef unsigned u32; typedef unsigned long long u64; typedef unsigned short u16;

// ---- workspace layout (u32 offsets) ----
#define OH1   0                   // NREP*4096 replica hists (zeroed)
#define OCNT  (NREP*4096)         // [0,1] unused, [2,3] cntB, [4,5] cntT
#define OSEL  (OCNT+6)            // D0,D1,above0,above1
#define OBAR  (OCNT+10)           // 2 grid-barrier counters
#define OZEND (OCNT+16)           // zeroed region end (=16400, even)
#define OLB   OZEND               // 2*CAPB u64 keys (8-aligned: even u32 offset)
#define OLT   (OLB + 4*CAPB)      // 2*CAPT u64 tie lists
#define OLSDV (OLT + 4*CAPT)      // NBLK*64 u32 per-block lsd vectors (non-atomic; all 64 written)

__device__ __forceinline__ u32 enc16(u32 b){ b &= 0xFFFFu; return (b & 0x8000u) ? ((~b)&0xFFFFu) : (b|0x8000u); }
__device__ __forceinline__ u32 dec16(u32 e){ return (e & 0x8000u) ? (e^0x8000u) : ((~e)&0xFFFFu); }
__device__ __forceinline__ float up16(u32 b){ return __uint_as_float((b&0xFFFFu)<<16); }
__device__ __forceinline__ u16 f2bf(float f){ u32 u=__float_as_uint(f); return (u16)((u + 0x7FFFu + ((u>>16)&1u))>>16); }

// packed u16 max (both channels at once); heat is positive bf16 so raw-u16 order == float order
__device__ __forceinline__ u32 pkmaxu16(u32 a, u32 b){
  u32 d; asm("v_pk_max_u16 %0, %1, %2" : "=v"(d) : "v"(a), "v"(b)); return d;
}

// one wave: largest bin D in bins[0..2047] with suffix-count >= need;
// Aout = count strictly above D.
__device__ __forceinline__ void wave_sel2048(const u32* bins, u32 need, int* Dout, u32* Aout){
  int lane = threadIdx.x & 63;
  u32 s = 0;
  #pragma unroll
  for(int k=0;k<32;++k) s += bins[lane*32+k];
  u32 c = s;
  #pragma unroll
  for(int off=1;off<64;off<<=1){
    u32 v = __shfl_down(c, off, 64);
    if(lane + off < 64) c += v;
  }
  u32 cnext = __shfl_down(c, 1, 64); if(lane==63) cnext = 0u;
  u64 m = __ballot(c >= need);
  if(m == 0ull){ if(lane==0){ *Dout = 0; *Aout = 0u; } return; }
  int L = 63 - __builtin_clzll((unsigned long long)m);
  if(lane == L){
    u32 above = cnext; int D = 32*L;
    for(int b=32*L+31; b>=32*L; --b){
      u32 h = bins[b];
      if(above + h >= need){ D = b; break; }
      above += h;
    }
    *Dout = D; *Aout = above;
  }
}

// LDS overlay: phases A/B vs phase C are time-disjoint
union SMem {
  struct {                       // phases A1/B'/A2: ~34.3 KB
    u32 lh[4096];
    u32 lsdl[64];
    u64 bbuf[2][CAPB];           // per-block B-class buffer (<=99 total grid-wide)
    u64 tbuf[2][LTCAP];          // per-block tie buffer (expected ~70/block)
  } ab;
  struct {                       // phase C: ~48 KB (single channel per block; tidx now LDS)
    u32 tidxS[CAPT];             // r14: was global scratch (2 latency RTs) -> LDS
    u32 h2s[2048];
    u64 keysS[CAPB];
    u32 selS[CAPB];
    u32 wbitsS[64];
    u32 lsdS[32];
    u32 hdr[10];
    float val[TOPK]; int vidx[TOPK];
    float cbox[TOPK][4]; float cscore[TOPK]; float area[TOPK];
    int sup[TOPK]; int slotv[TOPK];
    u64 nbits[2*TOPK];
  } c;
};

__device__ __forceinline__ void grid_arrive(u32* ctr){
  __hip_atomic_fetch_add(ctr, 1u, __ATOMIC_RELEASE, __HIP_MEMORY_SCOPE_AGENT);
}
// relaxed poll + single acquire fence (r12)
__device__ __forceinline__ void grid_wait(u32* ctr, u32 target){
  while(__hip_atomic_load(ctr, __ATOMIC_RELAXED, __HIP_MEMORY_SCOPE_AGENT) < target)
    __builtin_amdgcn_s_sleep(2);
  __builtin_amdgcn_fence(__ATOMIC_ACQUIRE, "agent");
}

__global__ __launch_bounds__(1024, 4) void fused_kernel(
    const u32* __restrict__ hm, u32* __restrict__ ws,
    const u32* __restrict__ szm, const u16* __restrict__ offm,
    const u16* __restrict__ orig, u16* __restrict__ out){
  __shared__ SMem S;
  __shared__ int Dsh[2]; __shared__ u32 Ash[2];
  __shared__ u32 bcntS[2], tcntS[2], bbaseS[2], tbaseS[2];
  __shared__ int selcS, selc2S, BvS, LshS, tcS;
  __shared__ u64 suppS[2];
  __shared__ int cS, srS, scS;

  int tid = threadIdx.x, lane = tid & 63;

  // ================= phase A1: peak histogram only (packed separable max) ======
  for(int i=tid;i<4096;i+=1024) S.ab.lh[i]=0u;
  __syncthreads();
  for(int vb = blockIdx.x; vb < VBTOT; vb += NBLK){
    int p = (vb*1024 + tid)*4;
    int y = p / IW, x = p - y*IW;
    const u32* R1 = hm + y*IW;
    const u32* R0 = y ? R1 - IW : R1;
    const u32* R2 = (y < IH-1) ? R1 + IW : R1;
    uint4 c0 = *(const uint4*)(R0+x), c1 = *(const uint4*)(R1+x), c2 = *(const uint4*)(R2+x);
    int xl = x ? x-1 : 0, xr = (x+4 < IW) ? x+4 : IW-1;
    u32 a0[6] = {R0[xl], c0.x, c0.y, c0.z, c0.w, R0[xr]};
    u32 a1[6] = {R1[xl], c1.x, c1.y, c1.z, c1.w, R1[xr]};
    u32 a2[6] = {R2[xl], c2.x, c2.y, c2.z, c2.w, R2[xr]};
    u32 v[6], w[6];
    #pragma unroll
    for(int k=0;k<6;++k){ w[k] = pkmaxu16(a0[k], a2[k]); v[k] = pkmaxu16(w[k], a1[k]); }
    #pragma unroll
    for(int j=0;j<4;++j){
      u32 m = pkmaxu16(pkmaxu16(v[j], w[j+1]), v[j+2]);   // 8 neighbors, center excluded
      u32 cc = a1[j+1];
      u32 cl = cc & 0xFFFFu, chv = cc >> 16;
      if(cl  >= (m & 0xFFFFu)) atomicAdd(&S.ab.lh[enc16(cl)>>5], 1u);
      if(chv >= (m >> 16))     atomicAdd(&S.ab.lh[2048 + (enc16(chv)>>5)], 1u);
    }
  }
  __syncthreads();
  // r14 A-change: flush to replica hist (hot-bin chain 192 -> 48), rotated order
  {
    u32 rot = ((u32)blockIdx.x * 97u) & 4095u;
    u32* H = ws + OH1 + ((u32)blockIdx.x & (NREP-1))*4096u;
    for(int i=tid;i<4096;i+=1024){
      u32 b = ((u32)i + rot) & 4095u;
      if(S.ab.lh[b]) atomicAdd(&H[b], S.ab.lh[b]);
    }
  }

  // ---- grid barrier 1 ----
  __syncthreads();
  if(tid==0){ grid_arrive(&ws[OBAR]); grid_wait(&ws[OBAR], (u32)NBLK); }
  __syncthreads();

  // ================= phase B': D/above from summed replica hists ===============
  for(int i=tid;i<4096;i+=1024)
    S.ab.lh[i] = ws[OH1+i] + ws[OH1+4096+i] + ws[OH1+8192+i] + ws[OH1+12288+i];
  if(tid < 64) S.ab.lsdl[tid] = 0u;
  if(tid < 2){ bcntS[tid] = 0u; tcntS[tid] = 0u; }
  __syncthreads();
  if(tid < 64)       wave_sel2048(S.ab.lh,        (u32)TOPK, &Dsh[0], &Ash[0]);
  else if(tid < 128) wave_sel2048(S.ab.lh + 2048, (u32)TOPK, &Dsh[1], &Ash[1]);
  __syncthreads();
  if(blockIdx.x == 0 && tid < 2){ ws[OSEL+tid] = (u32)Dsh[tid]; ws[OSEL+2+tid] = Ash[tid]; }

  // ============ phase A2: prefiltered re-scan, LDS-aggregated sparse emission ====
  {
    u32 thrD0 = (u32)Dsh[0] << 5, thrD1 = (u32)Dsh[1] << 5;
    u64* listBw = (u64*)(ws + OLB);
    u64* tieW   = (u64*)(ws + OLT);
    for(int vb = blockIdx.x; vb < VBTOT; vb += NBLK){
      int p = (vb*1024 + tid)*4;
      int y = p / IW, x = p - y*IW;
      const u32* R1 = hm + y*IW;
      uint4 c1v = *(const uint4*)(R1+x);
      u32 cen[4] = {c1v.x, c1v.y, c1v.z, c1v.w};
      const u32* R0 = y ? R1 - IW : R1;
      const u32* R2 = (y < IH-1) ? R1 + IW : R1;
      #pragma unroll
      for(int j=0;j<4;++j){
        u32 cc = cen[j];
        u32 cl = cc & 0xFFFFu, chv = cc >> 16;
        u32 e0 = enc16(cl), e1 = enc16(chv);
        bool cand0 = (e0 >= thrD0), cand1 = (e1 >= thrD1);
        if(!(cand0 || cand1)) continue;         // ~0.4% pass rate
        int xx = x + j;
        int xm = xx ? xx-1 : 0, xp = (xx+1 < IW) ? xx+1 : IW-1;
        u32 n0a=R0[xm], n0b=R0[xx], n0c=R0[xp];
        u32 n1a=R1[xm],             n1c=R1[xp];
        u32 n2a=R2[xm], n2b=R2[xx], n2c=R2[xp];
        u32 m0=0u, m1=0u, t;
        t=n0a&0xFFFFu; m0=t>m0?t:m0;  t=n0a>>16; m1=t>m1?t:m1;
        t=n0b&0xFFFFu; m0=t>m0?t:m0;  t=n0b>>16; m1=t>m1?t:m1;
        t=n0c&0xFFFFu; m0=t>m0?t:m0;  t=n0c>>16; m1=t>m1?t:m1;
        t=n1a&0xFFFFu; m0=t>m0?t:m0;  t=n1a>>16; m1=t>m1?t:m1;
        t=n1c&0xFFFFu; m0=t>m0?t:m0;  t=n1c>>16; m1=t>m1?t:m1;
        t=n2a&0xFFFFu; m0=t>m0?t:m0;  t=n2a>>16; m1=t>m1?t:m1;
        t=n2b&0xFFFFu; m0=t>m0?t:m0;  t=n2b>>16; m1=t>m1?t:m1;
        t=n2c&0xFFFFu; m0=t>m0?t:m0;  t=n2c>>16; m1=t>m1?t:m1;
        u32 idx = (u32)(p + j);
        u64 key0 = ((u64)e0<<32) | (u32)(~idx);
        u64 key1 = ((u64)e1<<32) | (u32)(~idx);
        if(cand0 && cl >= m0){
          if((e0>>5) > (u32)Dsh[0]){
            u32 pos = atomicAdd(&bcntS[0], 1u);       // <=99 grid-wide: always fits
            if(pos < CAPB) S.ab.bbuf[0][pos] = key0;
          } else {
            u32 pos = atomicAdd(&tcntS[0], 1u);
            if(pos < LTCAP) S.ab.tbuf[0][pos] = key0;
            else { u32 g = atomicAdd(&ws[OCNT+4], 1u); if(g < CAPT) tieW[g] = key0; }
            atomicAdd(&S.ab.lsdl[e0 & 31u], 1u);
          }
        }
        if(cand1 && chv >= m1){
          if((e1>>5) > (u32)Dsh[1]){
            u32 pos = atomicAdd(&bcntS[1], 1u);
            if(pos < CAPB) S.ab.bbuf[1][pos] = key1;
          } else {
            u32 pos = atomicAdd(&tcntS[1], 1u);
            if(pos < LTCAP) S.ab.tbuf[1][pos] = key1;
            else { u32 g = atomicAdd(&ws[OCNT+5], 1u); if(g < CAPT) tieW[CAPT + g] = key1; }
            atomicAdd(&S.ab.lsdl[32 + (e1 & 31u)], 1u);
          }
        }
      }
    }
    __syncthreads();
    // ---- block-level flush ----
    if(tid < 64) ws[OLSDV + (u32)blockIdx.x*64u + (u32)tid] = S.ab.lsdl[tid];
    if(tid >= 64 && tid < 66){
      int c2 = tid - 64;
      u32 n = bcntS[c2]; if(n > CAPB) n = CAPB;
      bcntS[c2] = n;
      bbaseS[c2] = n ? atomicAdd(&ws[OCNT+2+c2], n) : 0u;
    } else if(tid >= 66 && tid < 68){
      int ch2 = tid - 66;
      u32 n = tcntS[ch2]; if(n > LTCAP) n = LTCAP;
      tcntS[ch2] = n;
      tbaseS[ch2] = n ? atomicAdd(&ws[OCNT+4+ch2], n) : 0u;
    }
    __syncthreads();
    for(int ch2=0; ch2<2; ++ch2){
      u32 n = bcntS[ch2], base = bbaseS[ch2];
      for(u32 i=tid;i<n;i+=1024){
        u32 g = base + i;
        if(g < CAPB) listBw[ch2*CAPB + g] = S.ab.bbuf[ch2][i];
      }
      n = tcntS[ch2]; base = tbaseS[ch2];
      for(u32 i=tid;i<n;i+=1024){
        u32 g = base + i;
        if(g < CAPT) tieW[ch2*CAPT + g] = S.ab.tbuf[ch2][i];
      }
    }
  }

  // ---- grid barrier 2: blocks >=2 arrive and exit; blocks 0,1 spin ----
  __syncthreads();
  if(tid==0) grid_arrive(&ws[OBAR+1]);
  if(blockIdx.x >= 2) return;
  if(tid==0) grid_wait(&ws[OBAR+1], (u32)NBLK);
  __syncthreads();

  // ================= phase C: finalize — block 0 = ch0 (boxes/NMS), block 1 = ch1 (nose) ====
  {
    int ch = (int)blockIdx.x;

    // ---- C.1: batched control loads + zeroing ----
    if(tid < 10) S.c.hdr[tid] = ws[OCNT + tid];      // OCNT..OSEL contiguous
    if(tid < 32) S.c.lsdS[tid] = 0u;
    for(int i=tid;i<2048;i+=1024) S.c.h2s[i] = 0u;
    if(tid < 64) S.c.wbitsS[tid] = 0u;
    if(tid == 0){ selcS = 0; selc2S = 0; BvS = 0; LshS = 0; tcS = 0; }
    if(tid < TOPK){ S.c.val[tid]=0.0f; S.c.vidx[tid]=0; }
    __syncthreads();

    int nB = (int)S.c.hdr[2+ch]; if(nB > CAPB) nB = CAPB;
    int nT = (int)S.c.hdr[4+ch]; if(nT > CAPT) nT = CAPT;
    int D  = (int)S.c.hdr[6+ch];
    u32 above = S.c.hdr[8+ch];
    const u64* listB = ((const u64*)(ws + OLB)) + ch*CAPB;
    const u64* tie   = ((const u64*)(ws + OLT)) + ch*CAPT;

    // ---- C.1b: reduce per-block lsd vectors ----
    if(tid < 512){
      int c2 = tid & 31, g = tid >> 5;               // 16 groups x 32 classes
      u32 s = 0;
      for(int b = g; b < NBLK; b += 16) s += ws[OLSDV + (u32)b*64u + (u32)(ch*32 + c2)];
      if(s) atomicAdd(&S.c.lsdS[c2], s);
    }
    for(int i=tid;i<nB;i+=1024) S.c.keysS[i] = listB[i];
    __syncthreads();

    // ---- C.2: wave-parallel threshold pick ----
    if(tid < 64){
      u32 h = (lane < 32) ? S.c.lsdS[lane] : 0u;
      u32 c = h;
      #pragma unroll
      for(int off=1;off<32;off<<=1){
        u32 v = __shfl_down(c, off, 64);
        if(lane + off < 32) c += v;
      }
      u32 need2 = (u32)TOPK - above;     // in [1,100]
      u64 m = __ballot(lane >= 1 && lane < 32 && c >= need2);
      if(lane == 0){
        LshS = m ? (63 - __builtin_clzll((unsigned long long)m)) : 0;
        selcS = nB;
      }
    }
    __syncthreads();
    u32 thr = ((u32)D<<5) | (u32)LshS;
    float tval = up16(dec16(thr));

    // ---- C.3: single streamed pass (tie indices -> LDS, no global RT) ----
    for(int base2=0; base2<nT; base2+=1024){
      int i = base2 + tid;
      bool act = (i < nT);
      u64 k = 0; u32 e = 0, idx = 0;
      if(act){ k = tie[i]; e = (u32)(k>>32); idx = ~(u32)(k & 0xFFFFFFFFu); }
      if(act && e > thr){
        int pos = atomicAdd(&selcS, 1); if(pos < CAPB) S.c.keysS[pos] = k;
      }
      bool isT = act && (e == thr);
      u64 mk = __ballot(isT);
      if(mk){
        u32 cw = __popcll(mk), b;
        if(lane==0) b = (u32)atomicAdd(&tcS, (int)cw);
        b = __shfl(b, 0);
        if(isT){
          u32 pos = b + __popcll(mk & ((1ull<<lane)-1ull));
          if(pos < CAPT) S.c.tidxS[pos] = idx;
        }
      }
      if(isT) atomicAdd(&S.c.h2s[idx>>11], 1u);
    }
    __syncthreads();

    // ---- C.4: rank-sort keys; wave-parallel B-select ----
    int nA = selcS; if(nA > CAPB) nA = CAPB; if(nA > TOPK) nA = TOPK;
    int need = TOPK - nA;
    if(tid < nA){
      u64 kreg = S.c.keysS[tid];
      int r = 0;
      for(int j=0;j<nA;++j) r += (S.c.keysS[j] > kreg);
      if(r < TOPK){
        S.c.val[r] = up16(dec16((u32)(kreg>>32)));
        S.c.vidx[r] = (int)(~(u32)(kreg & 0xFFFFFFFFu));
      }
    }
    if(tid < 64){
      const u32* hh = S.c.h2s;
      int base = lane*32;
      u32 s = 0;
      #pragma unroll
      for(int k2=0;k2<32;++k2) s += hh[base+k2];
      u32 c = s;
      #pragma unroll
      for(int off=1;off<64;off<<=1){
        u32 v = __shfl_up(c, off, 64);
        if(lane >= off) c += v;
      }
      u64 m = __ballot(need > 0 && c >= (u32)need);
      int L = m ? (int)(__ffsll((unsigned long long)m) - 1) : -1;
      if(L >= 0 && lane == L){
        u32 hb[32];
        #pragma unroll
        for(int k2=0;k2<32;++k2) hb[k2] = hh[base+k2];
        u32 cum2 = c - s;
        int Bsel = base;
        #pragma unroll
        for(int k2=0;k2<32;++k2){
          if(cum2 + hb[k2] >= (u32)need){ Bsel = base+k2; break; }
          cum2 += hb[k2];
        }
        BvS = Bsel;
      }
    }
    __syncthreads();

    // ---- C.5: compact-tie pass (LDS source) ----
    int B = BvS;
    int tc = tcS; if(tc > CAPT) tc = CAPT;
    if(need > 0){
      for(int i=tid;i<tc;i+=1024){
        u32 idx = S.c.tidxS[i];
        int b = (int)(idx>>11);
        if(b < B){
          int pos = atomicAdd(&selc2S, 1);
          if(pos < CAPB) S.c.selS[pos] = idx;
        } else if(b == B){
          atomicOr(&S.c.wbitsS[(idx&2047)>>5], 1u<<(idx&31));
        }
      }
    }
    __syncthreads();

    // ---- C.6: order tie winners ----
    int sc = selc2S; if(sc > CAPB) sc = CAPB;
    if(need > 0 && tid < sc){
      u32 v = S.c.selS[tid];
      int r = 0;
      for(int j=0;j<sc;++j) r += (S.c.selS[j] < v);
      if(nA + r < TOPK){ S.c.val[nA+r] = tval; S.c.vidx[nA+r] = (int)v; }
    }
    if(need > 0 && tid < 64){
      u32 bits = S.c.wbitsS[tid];
      u32 cnt = __popc(bits);
      u32 incl = cnt;
      #pragma unroll
      for(int off=1;off<64;off<<=1){
        u32 v = __shfl_up(incl, off, 64);
        if(lane >= off) incl += v;
      }
      int excl = (int)(incl - cnt);
      int rem = need - sc;
      int pos = nA + sc + excl;
      int j = 0;
      while(bits){
        int l = __ffs(bits) - 1; bits &= bits - 1;
        if(excl + j < rem && pos + j < TOPK){
          S.c.val[pos+j] = tval;
          S.c.vidx[pos+j] = (int)(((u32)B<<11) | ((u32)tid<<5) | (u32)l);
        }
        ++j;
      }
    }
    __syncthreads();

    // ================= per-channel epilogues (fully independent) =================
    float ry = up16(orig[0]) / 1536.0f;
    float rx = up16(orig[1]) / 1536.0f;

    if(ch == 1){
      if(tid == 0){ cS = 0; srS = 0; scS = 0; }
      __syncthreads();
      if(tid < TOPK && S.c.val[tid] > 0.5f){
        atomicAdd(&cS, 1);
        atomicAdd(&srS, S.c.vidx[tid] / IW);
        atomicAdd(&scS, S.c.vidx[tid] % IW);
      }
      if(tid < TOPK) out[610 + tid] = f2bf(S.c.val[tid] > 0.5f ? S.c.val[tid] : -1.0f);
      __syncthreads();
      if(tid == 0){
        int c = cS < 1 ? 1 : cS;
        int meanr = srS / c, meanc = scS / c;
        float lfy = (float)meanr, lfx = (float)meanc;
        out[600] = f2bf(lfy * ry);
        out[601] = f2bf(lfx * rx);
        const u16* op = offm + ((size_t)meanr*IW + meanc)*8;
        for(int p=0;p<4;++p){
          out[602 + p*2 + 0] = f2bf((lfy - up16(op[p*2+0])) * ry);
          out[602 + p*2 + 1] = f2bf((lfx - up16(op[p*2+1])) * rx);
        }
      }
      return;
    }

    // ch == 0: boxes + NMS + out[0..599]
    if(tid < TOPK){
      int idx = S.c.vidx[tid];
      int r = idx / IW, c = idx - r*IW;
      float score = S.c.val[tid];
      u32 sz = szm[idx];
      float sy = up16(sz), sx = up16(sz>>16);
      float cy = (float)r, cx = (float)c;
      float tly = fmaxf(cy - sy*0.5f, 0.0f);
      float tlx = fmaxf(cx - sx*0.5f, 0.0f);
      float bry = fminf(cy + sy*0.5f, 1535.0f);
      float brx = fminf(cx + sx*0.5f, 1535.0f);
      bool mk = score > 0.3f;
      float b0 = mk ? tly*ry : -1.0f;
      float b1 = mk ? tlx*rx : -1.0f;
      float b2 = mk ? bry*ry : -1.0f;
      float b3 = mk ? brx*rx : -1.0f;
      S.c.cbox[tid][0]=b0; S.c.cbox[tid][1]=b1; S.c.cbox[tid][2]=b2; S.c.cbox[tid][3]=b3;
      S.c.cscore[tid] = mk ? score : -1.0f;
      S.c.area[tid] = fmaxf(b2-b0,0.0f) * fmaxf(b3-b1,0.0f);
    }
    if(tid < 2*TOPK) S.c.nbits[tid] = 0ull;
    __syncthreads();

    // r14: stride 1024 (was 512 — every pair was computed twice by the 1024-thread block)
    for(int t=tid; t<TOPK*TOPK; t+=1024){
      int i = t / TOPK, j = t - i*TOPK;
      if(j > i){
        float iy1 = fmaxf(S.c.cbox[i][0], S.c.cbox[j][0]);
        float ix1 = fmaxf(S.c.cbox[i][1], S.c.cbox[j][1]);
        float iy2 = fminf(S.c.cbox[i][2], S.c.cbox[j][2]);
        float ix2 = fminf(S.c.cbox[i][3], S.c.cbox[j][3]);
        float inter = fmaxf(iy2-iy1,0.0f) * fmaxf(ix2-ix1,0.0f);
        float uni = (S.c.area[i] + S.c.area[j]) - inter;
        if(inter / fmaxf(uni, 1e-8f) > 0.5f)
          atomicOr(&S.c.nbits[i*2 + (j>>6)], 1ull << (j&63));
      }
    }
    __syncthreads();
    // serial recurrence, register-batched LDS prefetch (10 rows/batch)
    if(tid == 0){
      u64 s0 = 0ull, s1 = 0ull;
      for(int base=0;base<TOPK;base+=10){
        u64 buf[20];
        #pragma unroll
        for(int k=0;k<20;++k) buf[k] = S.c.nbits[2*base+k];
        #pragma unroll
        for(int k=0;k<10;++k){
          int i = base+k;
          bool su = (i<64) ? ((s0>>i)&1ull) : ((s1>>(i-64))&1ull);
          if(!su){ s0 |= buf[2*k]; s1 |= buf[2*k+1]; }
        }
      }
      suppS[0] = s0; suppS[1] = s1;
    }
    __syncthreads();
    if(tid < TOPK) S.c.sup[tid] = (int)((suppS[tid>>6] >> (tid&63)) & 1ull);
    __syncthreads();

    if(tid < TOPK){
      int kbefore = 0, sbefore = 0, ktot = 0;
      for(int j=0;j<TOPK;++j){
        int sj = S.c.sup[j];
        ktot += (1 - sj);
        if(j < tid){ kbefore += (1 - sj); sbefore += sj; }
      }
      int slot = S.c.sup[tid] ? (ktot + sbefore) : kbefore;
      S.c.slotv[slot] = tid;
    }
    __syncthreads();

    if(tid < TOPK){
      int s = S.c.slotv[tid];
      bool ks = !S.c.sup[s];
      u16 row[6];
      if(ks){
        for(int d=0;d<4;++d){
          float v = S.c.cbox[s][d];
          row[d] = (v == -1.0f || v == 0.0f) ? (u16)BF_INF16 : f2bf(v);
        }
        row[4] = f2bf(S.c.cscore[s]);
      } else {
        for(int d=0;d<4;++d) row[d] = (u16)BF_INF16;
        row[4] = 0;
      }
      row[5] = 0;
      for(int d=0;d<6;++d) out[tid*6 + d] = row[d];
    }
  }
}

extern "C" void kernel_launch(void* const* d_in, const int* in_sizes, int n_in,
                              void* d_out, int out_size, void* d_ws, size_t ws_size,
                              hipStream_t stream) {
  const u32* heat = (const u32*)d_in[0];   // bf16 pairs (ch1<<16|ch0) per pixel
  const u16* offm = (const u16*)d_in[1];
  const u32* szm  = (const u32*)d_in[2];
  const u16* orig = (const u16*)d_in[3];
  u16* out = (u16*)d_out;
  u32* ws = (u32*)d_ws;

  hipMemsetAsync(ws, 0, OZEND*sizeof(u32), stream);   // replica hists + counters + sel + barriers
  fused_kernel<<<NBLK, 1024, 0, stream>>>(heat, ws, szm, offm, orig, out);
}

// Round 16
// 166.412 us; speedup vs baseline: 1.2496x; 1.0124x over previous
//
#include <hip/hip_runtime.h>
#include <cstdint>

#define IW 1536
#define IH 1536
#define TOPK 100
#define CAPB 128       // above-threshold keys (provably <=99 real entries)
#define CAPT 8192      // tie-class cap per channel (expected ~4.6k)
#define BF_INF16 0x7F7Fu  // bf16 max-finite stand-in for +inf (inf-inf=NaN in comparator)

#define NBLK 192       // ONLY proven-safe spin-grid width on this harness (8/8 passes; >192: 0/2)
#define VBTOT 576      // virtual scan tiles (4096 px each), static partition
#define LTCAP 1024     // per-block LDS tie buffer (expected ~70/block)
#define NREP 4         // A1 hist replicas (hot-bin chain 192 -> 48)

typedef unsigned u32; typedef unsigned long long u64; typedef unsigned short u16;

// ---- workspace layout (u32 offsets) ----
#define OH1   0                   // NREP*4096 replica hists (zeroed)
#define OCNT  (NREP*4096)         // [0,1] unused, [2,3] cntB, [4,5] cntT
#define OSEL  (OCNT+6)            // D0,D1,above0,above1
#define OBAR  (OCNT+10)           // 2 grid-barrier counters
#define OZEND (OCNT+16)           // zeroed region end (=16400, even)
#define OLB   OZEND               // 2*CAPB u64 keys (8-aligned: even u32 offset)
#define OLT   (OLB + 4*CAPB)      // 2*CAPT u64 tie lists
#define OLSDV (OLT + 4*CAPT)      // NBLK*64 u32 per-block lsd vectors (non-atomic; all 64 written)

__device__ __forceinline__ u32 enc16(u32 b){ b &= 0xFFFFu; return (b & 0x8000u) ? ((~b)&0xFFFFu) : (b|0x8000u); }
__device__ __forceinline__ u32 dec16(u32 e){ return (e & 0x8000u) ? (e^0x8000u) : ((~e)&0xFFFFu); }
__device__ __forceinline__ float up16(u32 b){ return __uint_as_float((b&0xFFFFu)<<16); }
__device__ __forceinline__ u16 f2bf(float f){ u32 u=__float_as_uint(f); return (u16)((u + 0x7FFFu + ((u>>16)&1u))>>16); }

// packed u16 max (both channels at once); heat is positive bf16 so raw-u16 order == float order
__device__ __forceinline__ u32 pkmaxu16(u32 a, u32 b){
  u32 d; asm("v_pk_max_u16 %0, %1, %2" : "=v"(d) : "v"(a), "v"(b)); return d;
}

// one wave: largest bin D in bins[0..2047] with suffix-count >= need;
// Aout = count strictly above D.
__device__ __forceinline__ void wave_sel2048(const u32* bins, u32 need, int* Dout, u32* Aout){
  int lane = threadIdx.x & 63;
  u32 s = 0;
  #pragma unroll
  for(int k=0;k<32;++k) s += bins[lane*32+k];
  u32 c = s;
  #pragma unroll
  for(int off=1;off<64;off<<=1){
    u32 v = __shfl_down(c, off, 64);
    if(lane + off < 64) c += v;
  }
  u32 cnext = __shfl_down(c, 1, 64); if(lane==63) cnext = 0u;
  u64 m = __ballot(c >= need);
  if(m == 0ull){ if(lane==0){ *Dout = 0; *Aout = 0u; } return; }
  int L = 63 - __builtin_clzll((unsigned long long)m);
  if(lane == L){
    u32 above = cnext; int D = 32*L;
    for(int b=32*L+31; b>=32*L; --b){
      u32 h = bins[b];
      if(above + h >= need){ D = b; break; }
      above += h;
    }
    *Dout = D; *Aout = above;
  }
}

// LDS overlay: phases A/B vs phase C are time-disjoint
union SMem {
  struct {                       // phases A1/B'/A2: ~34.3 KB
    u32 lh[4096];
    u32 lsdl[64];
    u64 bbuf[2][CAPB];           // per-block B-class buffer (<=99 total grid-wide)
    u64 tbuf[2][LTCAP];          // per-block tie buffer (expected ~70/block)
  } ab;
  struct {                       // phase C: ~48 KB (single channel per block; tidx in LDS)
    u32 tidxS[CAPT];
    u32 h2s[2048];
    u64 keysS[CAPB];
    u32 selS[CAPB];
    u32 wbitsS[64];
    u32 lsdS[32];
    u32 hdr[10];
    float val[TOPK]; int vidx[TOPK];
    float cbox[TOPK][4]; float cscore[TOPK]; float area[TOPK];
    int sup[TOPK]; int slotv[TOPK];
    u64 nbits[2*TOPK];
  } c;
};

__device__ __forceinline__ void grid_arrive(u32* ctr){
  __hip_atomic_fetch_add(ctr, 1u, __ATOMIC_RELEASE, __HIP_MEMORY_SCOPE_AGENT);
}
// relaxed poll + single acquire fence (r12)
__device__ __forceinline__ void grid_wait(u32* ctr, u32 target){
  while(__hip_atomic_load(ctr, __ATOMIC_RELAXED, __HIP_MEMORY_SCOPE_AGENT) < target)
    __builtin_amdgcn_s_sleep(2);
  __builtin_amdgcn_fence(__ATOMIC_ACQUIRE, "agent");
}

__global__ __launch_bounds__(1024, 4) void fused_kernel(
    const u32* __restrict__ hm, u32* __restrict__ ws,
    const u32* __restrict__ szm, const u16* __restrict__ offm,
    const u16* __restrict__ orig, u16* __restrict__ out){
  __shared__ SMem S;
  __shared__ int Dsh[2]; __shared__ u32 Ash[2];
  __shared__ u32 bcntS[2], tcntS[2], bbaseS[2], tbaseS[2];
  __shared__ int selcS, selc2S, BvS, LshS, tcS;
  __shared__ u64 suppS[2];
  __shared__ int cS, srS, scS;

  int tid = threadIdx.x, lane = tid & 63;

  // ================= phase A1: peak histogram only (packed separable max) ======
  for(int i=tid;i<4096;i+=1024) S.ab.lh[i]=0u;
  __syncthreads();
  for(int vb = blockIdx.x; vb < VBTOT; vb += NBLK){
    int p = (vb*1024 + tid)*4;
    int y = p / IW, x = p - y*IW;
    const u32* R1 = hm + y*IW;
    const u32* R0 = y ? R1 - IW : R1;
    const u32* R2 = (y < IH-1) ? R1 + IW : R1;
    uint4 c0 = *(const uint4*)(R0+x), c1 = *(const uint4*)(R1+x), c2 = *(const uint4*)(R2+x);
    int xl = x ? x-1 : 0, xr = (x+4 < IW) ? x+4 : IW-1;
    u32 a0[6] = {R0[xl], c0.x, c0.y, c0.z, c0.w, R0[xr]};
    u32 a1[6] = {R1[xl], c1.x, c1.y, c1.z, c1.w, R1[xr]};
    u32 a2[6] = {R2[xl], c2.x, c2.y, c2.z, c2.w, R2[xr]};
    u32 v[6], w[6];
    #pragma unroll
    for(int k=0;k<6;++k){ w[k] = pkmaxu16(a0[k], a2[k]); v[k] = pkmaxu16(w[k], a1[k]); }
    #pragma unroll
    for(int j=0;j<4;++j){
      u32 m = pkmaxu16(pkmaxu16(v[j], w[j+1]), v[j+2]);   // 8 neighbors, center excluded
      u32 cc = a1[j+1];
      u32 cl = cc & 0xFFFFu, chv = cc >> 16;
      if(cl  >= (m & 0xFFFFu)) atomicAdd(&S.ab.lh[enc16(cl)>>5], 1u);
      if(chv >= (m >> 16))     atomicAdd(&S.ab.lh[2048 + (enc16(chv)>>5)], 1u);
    }
  }
  __syncthreads();
  // flush to replica hist (hot-bin chain 192 -> 48), rotated order
  {
    u32 rot = ((u32)blockIdx.x * 97u) & 4095u;
    u32* H = ws + OH1 + ((u32)blockIdx.x & (NREP-1))*4096u;
    for(int i=tid;i<4096;i+=1024){
      u32 b = ((u32)i + rot) & 4095u;
      if(S.ab.lh[b]) atomicAdd(&H[b], S.ab.lh[b]);
    }
  }

  // ---- grid barrier 1 ----
  __syncthreads();
  if(tid==0){ grid_arrive(&ws[OBAR]); grid_wait(&ws[OBAR], (u32)NBLK); }
  __syncthreads();

  // ================= phase B': D/above from summed replica hists ===============
  for(int i=tid;i<4096;i+=1024)
    S.ab.lh[i] = ws[OH1+i] + ws[OH1+4096+i] + ws[OH1+8192+i] + ws[OH1+12288+i];
  if(tid < 64) S.ab.lsdl[tid] = 0u;
  if(tid < 2){ bcntS[tid] = 0u; tcntS[tid] = 0u; }
  __syncthreads();
  if(tid < 64)       wave_sel2048(S.ab.lh,        (u32)TOPK, &Dsh[0], &Ash[0]);
  else if(tid < 128) wave_sel2048(S.ab.lh + 2048, (u32)TOPK, &Dsh[1], &Ash[1]);
  __syncthreads();
  if(blockIdx.x == 0 && tid < 2){ ws[OSEL+tid] = (u32)Dsh[tid]; ws[OSEL+2+tid] = Ash[tid]; }

  // ============ phase A2: prefiltered re-scan, LDS-aggregated sparse emission ====
  {
    u32 thrD0 = (u32)Dsh[0] << 5, thrD1 = (u32)Dsh[1] << 5;
    u64* listBw = (u64*)(ws + OLB);
    u64* tieW   = (u64*)(ws + OLT);
    for(int vb = blockIdx.x; vb < VBTOT; vb += NBLK){
      int p = (vb*1024 + tid)*4;
      int y = p / IW, x = p - y*IW;
      const u32* R1 = hm + y*IW;
      uint4 c1v = *(const uint4*)(R1+x);
      u32 cen[4] = {c1v.x, c1v.y, c1v.z, c1v.w};
      const u32* R0 = y ? R1 - IW : R1;
      const u32* R2 = (y < IH-1) ? R1 + IW : R1;
      #pragma unroll
      for(int j=0;j<4;++j){
        u32 cc = cen[j];
        u32 cl = cc & 0xFFFFu, chv = cc >> 16;
        u32 e0 = enc16(cl), e1 = enc16(chv);
        bool cand0 = (e0 >= thrD0), cand1 = (e1 >= thrD1);
        if(!(cand0 || cand1)) continue;         // ~0.4% pass rate
        int xx = x + j;
        int xm = xx ? xx-1 : 0, xp = (xx+1 < IW) ? xx+1 : IW-1;
        u32 n0a=R0[xm], n0b=R0[xx], n0c=R0[xp];
        u32 n1a=R1[xm],             n1c=R1[xp];
        u32 n2a=R2[xm], n2b=R2[xx], n2c=R2[xp];
        u32 m0=0u, m1=0u, t;
        t=n0a&0xFFFFu; m0=t>m0?t:m0;  t=n0a>>16; m1=t>m1?t:m1;
        t=n0b&0xFFFFu; m0=t>m0?t:m0;  t=n0b>>16; m1=t>m1?t:m1;
        t=n0c&0xFFFFu; m0=t>m0?t:m0;  t=n0c>>16; m1=t>m1?t:m1;
        t=n1a&0xFFFFu; m0=t>m0?t:m0;  t=n1a>>16; m1=t>m1?t:m1;
        t=n1c&0xFFFFu; m0=t>m0?t:m0;  t=n1c>>16; m1=t>m1?t:m1;
        t=n2a&0xFFFFu; m0=t>m0?t:m0;  t=n2a>>16; m1=t>m1?t:m1;
        t=n2b&0xFFFFu; m0=t>m0?t:m0;  t=n2b>>16; m1=t>m1?t:m1;
        t=n2c&0xFFFFu; m0=t>m0?t:m0;  t=n2c>>16; m1=t>m1?t:m1;
        u32 idx = (u32)(p + j);
        u64 key0 = ((u64)e0<<32) | (u32)(~idx);
        u64 key1 = ((u64)e1<<32) | (u32)(~idx);
        if(cand0 && cl >= m0){
          if((e0>>5) > (u32)Dsh[0]){
            u32 pos = atomicAdd(&bcntS[0], 1u);       // <=99 grid-wide: always fits
            if(pos < CAPB) S.ab.bbuf[0][pos] = key0;
          } else {
            u32 pos = atomicAdd(&tcntS[0], 1u);
            if(pos < LTCAP) S.ab.tbuf[0][pos] = key0;
            else { u32 g = atomicAdd(&ws[OCNT+4], 1u); if(g < CAPT) tieW[g] = key0; }
            atomicAdd(&S.ab.lsdl[e0 & 31u], 1u);
          }
        }
        if(cand1 && chv >= m1){
          if((e1>>5) > (u32)Dsh[1]){
            u32 pos = atomicAdd(&bcntS[1], 1u);
            if(pos < CAPB) S.ab.bbuf[1][pos] = key1;
          } else {
            u32 pos = atomicAdd(&tcntS[1], 1u);
            if(pos < LTCAP) S.ab.tbuf[1][pos] = key1;
            else { u32 g = atomicAdd(&ws[OCNT+5], 1u); if(g < CAPT) tieW[CAPT + g] = key1; }
            atomicAdd(&S.ab.lsdl[32 + (e1 & 31u)], 1u);
          }
        }
      }
    }
    __syncthreads();
    // ---- block-level flush ----
    if(tid < 64) ws[OLSDV + (u32)blockIdx.x*64u + (u32)tid] = S.ab.lsdl[tid];
    if(tid >= 64 && tid < 66){
      int c2 = tid - 64;
      u32 n = bcntS[c2]; if(n > CAPB) n = CAPB;
      bcntS[c2] = n;
      bbaseS[c2] = n ? atomicAdd(&ws[OCNT+2+c2], n) : 0u;
    } else if(tid >= 66 && tid < 68){
      int ch2 = tid - 66;
      u32 n = tcntS[ch2]; if(n > LTCAP) n = LTCAP;
      tcntS[ch2] = n;
      tbaseS[ch2] = n ? atomicAdd(&ws[OCNT+4+ch2], n) : 0u;
    }
    __syncthreads();
    for(int ch2=0; ch2<2; ++ch2){
      u32 n = bcntS[ch2], base = bbaseS[ch2];
      for(u32 i=tid;i<n;i+=1024){
        u32 g = base + i;
        if(g < CAPB) listBw[ch2*CAPB + g] = S.ab.bbuf[ch2][i];
      }
      n = tcntS[ch2]; base = tbaseS[ch2];
      for(u32 i=tid;i<n;i+=1024){
        u32 g = base + i;
        if(g < CAPT) tieW[ch2*CAPT + g] = S.ab.tbuf[ch2][i];
      }
    }
  }

  // ---- grid barrier 2: blocks >=2 arrive and exit; blocks 0,1 spin ----
  __syncthreads();
  if(tid==0) grid_arrive(&ws[OBAR+1]);
  if(blockIdx.x >= 2) return;
  if(tid==0) grid_wait(&ws[OBAR+1], (u32)NBLK);
  __syncthreads();

  // ================= phase C: finalize — block 0 = ch0 (boxes/NMS), block 1 = ch1 (nose) ====
  {
    int ch = (int)blockIdx.x;

    // ---- C.1: batched control loads + zeroing ----
    if(tid < 10) S.c.hdr[tid] = ws[OCNT + tid];      // OCNT..OSEL contiguous
    if(tid < 32) S.c.lsdS[tid] = 0u;
    for(int i=tid;i<2048;i+=1024) S.c.h2s[i] = 0u;
    if(tid < 64) S.c.wbitsS[tid] = 0u;
    if(tid == 0){ selcS = 0; selc2S = 0; BvS = 0; LshS = 0; tcS = 0; }
    if(tid < TOPK){ S.c.val[tid]=0.0f; S.c.vidx[tid]=0; }
    __syncthreads();

    int nB = (int)S.c.hdr[2+ch]; if(nB > CAPB) nB = CAPB;
    int nT = (int)S.c.hdr[4+ch]; if(nT > CAPT) nT = CAPT;
    int D  = (int)S.c.hdr[6+ch];
    u32 above = S.c.hdr[8+ch];
    const u64* listB = ((const u64*)(ws + OLB)) + ch*CAPB;
    const u64* tie   = ((const u64*)(ws + OLT)) + ch*CAPT;

    // ---- C.1b: reduce per-block lsd vectors ----
    if(tid < 512){
      int c2 = tid & 31, g = tid >> 5;               // 16 groups x 32 classes
      u32 s = 0;
      for(int b = g; b < NBLK; b += 16) s += ws[OLSDV + (u32)b*64u + (u32)(ch*32 + c2)];
      if(s) atomicAdd(&S.c.lsdS[c2], s);
    }
    for(int i=tid;i<nB;i+=1024) S.c.keysS[i] = listB[i];
    __syncthreads();

    // ---- C.2: wave-parallel threshold pick ----
    if(tid < 64){
      u32 h = (lane < 32) ? S.c.lsdS[lane] : 0u;
      u32 c = h;
      #pragma unroll
      for(int off=1;off<32;off<<=1){
        u32 v = __shfl_down(c, off, 64);
        if(lane + off < 32) c += v;
      }
      u32 need2 = (u32)TOPK - above;     // in [1,100]
      u64 m = __ballot(lane >= 1 && lane < 32 && c >= need2);
      if(lane == 0){
        LshS = m ? (63 - __builtin_clzll((unsigned long long)m)) : 0;
        selcS = nB;
      }
    }
    __syncthreads();
    u32 thr = ((u32)D<<5) | (u32)LshS;
    float tval = up16(dec16(thr));

    // ---- C.3: single streamed pass (tie indices -> LDS, no global RT) ----
    for(int base2=0; base2<nT; base2+=1024){
      int i = base2 + tid;
      bool act = (i < nT);
      u64 k = 0; u32 e = 0, idx = 0;
      if(act){ k = tie[i]; e = (u32)(k>>32); idx = ~(u32)(k & 0xFFFFFFFFu); }
      if(act && e > thr){
        int pos = atomicAdd(&selcS, 1); if(pos < CAPB) S.c.keysS[pos] = k;
      }
      bool isT = act && (e == thr);
      u64 mk = __ballot(isT);
      if(mk){
        u32 cw = __popcll(mk), b;
        if(lane==0) b = (u32)atomicAdd(&tcS, (int)cw);
        b = __shfl(b, 0);
        if(isT){
          u32 pos = b + __popcll(mk & ((1ull<<lane)-1ull));
          if(pos < CAPT) S.c.tidxS[pos] = idx;
        }
      }
      if(isT) atomicAdd(&S.c.h2s[idx>>11], 1u);
    }
    __syncthreads();

    // ---- C.4: rank-sort keys; wave-parallel B-select ----
    int nA = selcS; if(nA > CAPB) nA = CAPB; if(nA > TOPK) nA = TOPK;
    int need = TOPK - nA;
    if(tid < nA){
      u64 kreg = S.c.keysS[tid];
      int r = 0;
      for(int j=0;j<nA;++j) r += (S.c.keysS[j] > kreg);
      if(r < TOPK){
        S.c.val[r] = up16(dec16((u32)(kreg>>32)));
        S.c.vidx[r] = (int)(~(u32)(kreg & 0xFFFFFFFFu));
      }
    }
    if(tid < 64){
      const u32* hh = S.c.h2s;
      int base = lane*32;
      u32 s = 0;
      #pragma unroll
      for(int k2=0;k2<32;++k2) s += hh[base+k2];
      u32 c = s;
      #pragma unroll
      for(int off=1;off<64;off<<=1){
        u32 v = __shfl_up(c, off, 64);
        if(lane >= off) c += v;
      }
      u64 m = __ballot(need > 0 && c >= (u32)need);
      int L = m ? (int)(__ffsll((unsigned long long)m) - 1) : -1;
      if(L >= 0 && lane == L){
        u32 hb[32];
        #pragma unroll
        for(int k2=0;k2<32;++k2) hb[k2] = hh[base+k2];
        u32 cum2 = c - s;
        int Bsel = base;
        #pragma unroll
        for(int k2=0;k2<32;++k2){
          if(cum2 + hb[k2] >= (u32)need){ Bsel = base+k2; break; }
          cum2 += hb[k2];
        }
        BvS = Bsel;
      }
    }
    __syncthreads();

    // ---- C.5: compact-tie pass (LDS source) ----
    int B = BvS;
    int tc = tcS; if(tc > CAPT) tc = CAPT;
    if(need > 0){
      for(int i=tid;i<tc;i+=1024){
        u32 idx = S.c.tidxS[i];
        int b = (int)(idx>>11);
        if(b < B){
          int pos = atomicAdd(&selc2S, 1);
          if(pos < CAPB) S.c.selS[pos] = idx;
        } else if(b == B){
          atomicOr(&S.c.wbitsS[(idx&2047)>>5], 1u<<(idx&31));
        }
      }
    }
    __syncthreads();

    // ---- C.6: order tie winners ----
    int sc = selc2S; if(sc > CAPB) sc = CAPB;
    if(need > 0 && tid < sc){
      u32 v = S.c.selS[tid];
      int r = 0;
      for(int j=0;j<sc;++j) r += (S.c.selS[j] < v);
      if(nA + r < TOPK){ S.c.val[nA+r] = tval; S.c.vidx[nA+r] = (int)v; }
    }
    if(need > 0 && tid < 64){
      u32 bits = S.c.wbitsS[tid];
      u32 cnt = __popc(bits);
      u32 incl = cnt;
      #pragma unroll
      for(int off=1;off<64;off<<=1){
        u32 v = __shfl_up(incl, off, 64);
        if(lane >= off) incl += v;
      }
      int excl = (int)(incl - cnt);
      int rem = need - sc;
      int pos = nA + sc + excl;
      int j = 0;
      while(bits){
        int l = __ffs(bits) - 1; bits &= bits - 1;
        if(excl + j < rem && pos + j < TOPK){
          S.c.val[pos+j] = tval;
          S.c.vidx[pos+j] = (int)(((u32)B<<11) | ((u32)tid<<5) | (u32)l);
        }
        ++j;
      }
    }
    __syncthreads();

    // ================= per-channel epilogues (fully independent) =================
    float ry = up16(orig[0]) / 1536.0f;
    float rx = up16(orig[1]) / 1536.0f;

    if(ch == 1){
      if(tid == 0){ cS = 0; srS = 0; scS = 0; }
      __syncthreads();
      if(tid < TOPK && S.c.val[tid] > 0.5f){
        atomicAdd(&cS, 1);
        atomicAdd(&srS, S.c.vidx[tid] / IW);
        atomicAdd(&scS, S.c.vidx[tid] % IW);
      }
      if(tid < TOPK) out[610 + tid] = f2bf(S.c.val[tid] > 0.5f ? S.c.val[tid] : -1.0f);
      __syncthreads();
      if(tid == 0){
        int c = cS < 1 ? 1 : cS;
        int meanr = srS / c, meanc = scS / c;
        float lfy = (float)meanr, lfx = (float)meanc;
        out[600] = f2bf(lfy * ry);
        out[601] = f2bf(lfx * rx);
        const u16* op = offm + ((size_t)meanr*IW + meanc)*8;
        for(int p=0;p<4;++p){
          out[602 + p*2 + 0] = f2bf((lfy - up16(op[p*2+0])) * ry);
          out[602 + p*2 + 1] = f2bf((lfx - up16(op[p*2+1])) * rx);
        }
      }
      return;
    }

    // ch == 0: boxes + NMS + out[0..599]
    if(tid < TOPK){
      int idx = S.c.vidx[tid];
      int r = idx / IW, c = idx - r*IW;
      float score = S.c.val[tid];
      u32 sz = szm[idx];
      float sy = up16(sz), sx = up16(sz>>16);
      float cy = (float)r, cx = (float)c;
      float tly = fmaxf(cy - sy*0.5f, 0.0f);
      float tlx = fmaxf(cx - sx*0.5f, 0.0f);
      float bry = fminf(cy + sy*0.5f, 1535.0f);
      float brx = fminf(cx + sx*0.5f, 1535.0f);
      bool mk = score > 0.3f;
      float b0 = mk ? tly*ry : -1.0f;
      float b1 = mk ? tlx*rx : -1.0f;
      float b2 = mk ? bry*ry : -1.0f;
      float b3 = mk ? brx*rx : -1.0f;
      S.c.cbox[tid][0]=b0; S.c.cbox[tid][1]=b1; S.c.cbox[tid][2]=b2; S.c.cbox[tid][3]=b3;
      S.c.cscore[tid] = mk ? score : -1.0f;
      S.c.area[tid] = fmaxf(b2-b0,0.0f) * fmaxf(b3-b1,0.0f);
    }
    if(tid < 2*TOPK) S.c.nbits[tid] = 0ull;
    __syncthreads();

    for(int t=tid; t<TOPK*TOPK; t+=1024){
      int i = t / TOPK, j = t - i*TOPK;
      if(j > i){
        float iy1 = fmaxf(S.c.cbox[i][0], S.c.cbox[j][0]);
        float ix1 = fmaxf(S.c.cbox[i][1], S.c.cbox[j][1]);
        float iy2 = fminf(S.c.cbox[i][2], S.c.cbox[j][2]);
        float ix2 = fminf(S.c.cbox[i][3], S.c.cbox[j][3]);
        float inter = fmaxf(iy2-iy1,0.0f) * fmaxf(ix2-ix1,0.0f);
        float uni = (S.c.area[i] + S.c.area[j]) - inter;
        if(inter / fmaxf(uni, 1e-8f) > 0.5f)
          atomicOr(&S.c.nbits[i*2 + (j>>6)], 1ull << (j&63));
      }
    }
    __syncthreads();
    // serial recurrence, register-batched LDS prefetch (10 rows/batch)
    if(tid == 0){
      u64 s0 = 0ull, s1 = 0ull;
      for(int base=0;base<TOPK;base+=10){
        u64 buf[20];
        #pragma unroll
        for(int k=0;k<20;++k) buf[k] = S.c.nbits[2*base+k];
        #pragma unroll
        for(int k=0;k<10;++k){
          int i = base+k;
          bool su = (i<64) ? ((s0>>i)&1ull) : ((s1>>(i-64))&1ull);
          if(!su){ s0 |= buf[2*k]; s1 |= buf[2*k+1]; }
        }
      }
      suppS[0] = s0; suppS[1] = s1;
    }
    __syncthreads();
    if(tid < TOPK) S.c.sup[tid] = (int)((suppS[tid>>6] >> (tid&63)) & 1ull);
    __syncthreads();

    if(tid < TOPK){
      int kbefore = 0, sbefore = 0, ktot = 0;
      for(int j=0;j<TOPK;++j){
        int sj = S.c.sup[j];
        ktot += (1 - sj);
        if(j < tid){ kbefore += (1 - sj); sbefore += sj; }
      }
      int slot = S.c.sup[tid] ? (ktot + sbefore) : kbefore;
      S.c.slotv[slot] = tid;
    }
    __syncthreads();

    if(tid < TOPK){
      int s = S.c.slotv[tid];
      bool ks = !S.c.sup[s];
      u16 row[6];
      if(ks){
        for(int d=0;d<4;++d){
          float v = S.c.cbox[s][d];
          row[d] = (v == -1.0f || v == 0.0f) ? (u16)BF_INF16 : f2bf(v);
        }
        row[4] = f2bf(S.c.cscore[s]);
      } else {
        for(int d=0;d<4;++d) row[d] = (u16)BF_INF16;
        row[4] = 0;
      }
      row[5] = 0;
      for(int d=0;d<6;++d) out[tid*6 + d] = row[d];
    }
  }
}

extern "C" void kernel_launch(void* const* d_in, const int* in_sizes, int n_in,
                              void* d_out, int out_size, void* d_ws, size_t ws_size,
                              hipStream_t stream) {
  const u32* heat = (const u32*)d_in[0];   // bf16 pairs (ch1<<16|ch0) per pixel
  const u16* offm = (const u16*)d_in[1];
  const u32* szm  = (const u32*)d_in[2];
  const u16* orig = (const u16*)d_in[3];
  u16* out = (u16*)d_out;
  u32* ws = (u32*)d_ws;

  hipMemsetAsync(ws, 0, OZEND*sizeof(u32), stream);   // replica hists + counters + sel + barriers
  fused_kernel<<<NBLK, 1024, 0, stream>>>(heat, ws, szm, offm, orig, out);
}